// Round 5
// baseline (474.892 us; speedup 1.0000x reference)
//
#include <hip/hip_runtime.h>
#include <stdint.h>

#define K_DIM 4096
#define N_DIM 4096
#define KB    32          // K / 128
#define QMAXF 127.0f

typedef int v4i __attribute__((ext_vector_type(4)));

__device__ __forceinline__ void async_copy16(void* lds, const void* gptr) {
    __builtin_amdgcn_global_load_lds(
        (__attribute__((address_space(1))) void*)gptr,
        (__attribute__((address_space(3))) void*)lds, 16, 0, 0);
}

// ---------------- activation quant: per (row, 128-block) ----------------
__global__ __launch_bounds__(256) void act_quant_kernel(
    const float* __restrict__ x, int8_t* __restrict__ xq,
    float* __restrict__ xs_t, int M)
{
    const int t = threadIdx.x;
    for (int m = blockIdx.x; m < M; m += gridDim.x) {
        const float* xrow = x + (size_t)m * K_DIM;
        int8_t* qrow = xq + (size_t)m * K_DIM;

#pragma unroll
        for (int p = 0; p < 4; ++p) {
            const int base = p * 1024 + t * 4;
            float4 v = *(const float4*)(xrow + base);
            float a = fmaxf(fmaxf(fabsf(v.x), fabsf(v.y)), fmaxf(fabsf(v.z), fabsf(v.w)));
#pragma unroll
            for (int off = 1; off < 32; off <<= 1)
                a = fmaxf(a, __shfl_xor(a, off, 64));
            const float s = fmaxf(a / QMAXF, 1e-12f);
            const float inv = 1.0f / s;
            float q0 = fminf(fmaxf(rintf(v.x * inv), -128.f), 127.f);
            float q1 = fminf(fmaxf(rintf(v.y * inv), -128.f), 127.f);
            float q2 = fminf(fmaxf(rintf(v.z * inv), -128.f), 127.f);
            float q3 = fminf(fmaxf(rintf(v.w * inv), -128.f), 127.f);
            char4 pk;
            pk.x = (char)(int)q0; pk.y = (char)(int)q1;
            pk.z = (char)(int)q2; pk.w = (char)(int)q3;
            *(char4*)(qrow + base) = pk;
            if ((t & 31) == 0) {
                const int g = base >> 7;
                xs_t[(size_t)g * M + m] = s;         // transposed [kb][M]
            }
        }
    }
}

// ---------------- weight quant: per 128x128 block ----------------
__global__ __launch_bounds__(256) void weight_quant_kernel(
    const float* __restrict__ w, int8_t* __restrict__ wq, float* __restrict__ ws)
{
    const int nb = blockIdx.x >> 5;
    const int kb = blockIdx.x & 31;
    const int t  = threadIdx.x;
    const int n0 = nb * 128, k0 = kb * 128;

    float4 vals[16];
    float a = 0.f;
#pragma unroll
    for (int ii = 0; ii < 16; ++ii) {
        const int e = ii * 1024 + t * 4;
        const int row = e >> 7, col = e & 127;
        float4 v = *(const float4*)(w + (size_t)(n0 + row) * K_DIM + k0 + col);
        vals[ii] = v;
        a = fmaxf(a, fmaxf(fmaxf(fabsf(v.x), fabsf(v.y)), fmaxf(fabsf(v.z), fabsf(v.w))));
    }
#pragma unroll
    for (int off = 1; off < 64; off <<= 1)
        a = fmaxf(a, __shfl_xor(a, off, 64));
    __shared__ float wred[4];
    if ((t & 63) == 0) wred[t >> 6] = a;
    __syncthreads();
    a = fmaxf(fmaxf(wred[0], wred[1]), fmaxf(wred[2], wred[3]));
    const float s = fmaxf(a / QMAXF, 1e-12f);
    const float inv = 1.0f / s;
    if (t == 0) ws[nb * KB + kb] = s;

#pragma unroll
    for (int ii = 0; ii < 16; ++ii) {
        const int e = ii * 1024 + t * 4;
        const int row = e >> 7, col = e & 127;
        float4 v = vals[ii];
        char4 pk;
        pk.x = (char)(int)fminf(fmaxf(rintf(v.x * inv), -128.f), 127.f);
        pk.y = (char)(int)fminf(fmaxf(rintf(v.y * inv), -128.f), 127.f);
        pk.z = (char)(int)fminf(fmaxf(rintf(v.z * inv), -128.f), 127.f);
        pk.w = (char)(int)fminf(fmaxf(rintf(v.w * inv), -128.f), 127.f);
        *(char4*)(wq + (size_t)(n0 + row) * K_DIM + k0 + col) = pk;
    }
}

// ---------------- int8 GEMM v5: round-0 structure + double buffer ----------
// Post-mortem of v4 (8-phase lockstep, 213us, Mfma 27%): int8-dequant GEMM
// has VALU work (cvt+fmac per elem per kb) comparable to MFMA work; the
// per-phase barrier->lgkm->MFMA->barrier lockstep serializes the two pipes
// chip-wide (27+37=65% with no overlap). Round-0's loose structure hit
// 32+44=76% via m114 cross-wave MFMA||VALU overlap at 2.3 blocks/CU; its
// remaining ~24% loss was the single-buffer stage drain (syncthreads drains
// loads issued immediately before).
// v5 = round-0 128x128 tile, 4 waves, loose scheduling (ONE syncthreads per
// iter), LDS double-buffered (2x32KiB A/B + 2x0.5KiB xs = 66.5KiB -> still
// 2 blocks/CU): next-kb stages issue at iter START and are drained by the
// iter-END syncthreads, ~one full iter (~2500cyc) later. XOR swizzle,
// fragment addressing, epilogue identical to the harness-verified round-0.
// XCD-aware block swizzle (grid 2048, % 8 == 0).
__global__ __launch_bounds__(256, 2) void gemm_kernel(
    const int8_t* __restrict__ xq, const int8_t* __restrict__ wq,
    const float* __restrict__ xs_t, const float* __restrict__ ws,
    const float* __restrict__ bias, float* __restrict__ out, int M)
{
    __shared__ __align__(16) int8_t As[2][128 * 128];
    __shared__ __align__(16) int8_t Bs[2][128 * 128];
    __shared__ __align__(16) float  xs_lds[2][128];

    const int t    = threadIdx.x;
    const int lane = t & 63;
    const int wave = t >> 6;

    // XCD-aware bijective swizzle (grid 2048, divisible by 8)
    const int nwg  = gridDim.x;
    const int cpx  = nwg >> 3;
    const int bid  = blockIdx.x;
    const int tile = (bid & 7) * cpx + (bid >> 3);
    const int nbt  = tile & 31;           // N/128 = 32
    const int mbt  = tile >> 5;           // M/128 = 64
    const int n0   = nbt * 128;
    const int m0   = mbt * 128;

    const int wm    = (wave >> 1) * 64;
    const int wn    = (wave & 1) * 64;
    const int frow  = lane & 15;
    const int q     = lane >> 4;          // k-chunk index (0..3)
    const int quad4 = q * 4;
    const int sw0   = (q ^ (frow & 7)) * 16;
    const int wsrow = nbt * KB;           // block-uniform ws row

    // staging map: LDS slot ci holds global chunk (row=ci>>3, c=(ci&7)^(row&7))
    int st_off[4];
#pragma unroll
    for (int it = 0; it < 4; ++it) {
        const int ci  = it * 256 + t;
        const int row = ci >> 3;
        const int c   = (ci & 7) ^ (row & 7);
        st_off[it] = row * K_DIM + c * 16;
    }

    const int8_t* Abase = xq + (size_t)m0 * K_DIM;
    const int8_t* Bbase = wq + (size_t)n0 * K_DIM;

    float4 facc[4][4] = {};

    // ---- prologue: stage kb=0 into buffer 0 ----
#pragma unroll
    for (int it = 0; it < 4; ++it) {
        async_copy16(&As[0][(it * 256 + wave * 64) * 16], Abase + st_off[it]);
        async_copy16(&Bs[0][(it * 256 + wave * 64) * 16], Bbase + st_off[it]);
    }
    if (t < 32)
        async_copy16(&xs_lds[0][0], xs_t + m0 + t * 4);
    __syncthreads();

    for (int kb = 0; kb < KB; ++kb) {
        const int cur = kb & 1;
        const int nxt = cur ^ 1;

        // issue next-kb stages FIRST (oldest VM ops; drained by iter-end sync)
        if (kb + 1 < KB) {
            const int8_t* Agn = Abase + (size_t)(kb + 1) * 128;
            const int8_t* Bgn = Bbase + (size_t)(kb + 1) * 128;
#pragma unroll
            for (int it = 0; it < 4; ++it) {
                async_copy16(&As[nxt][(it * 256 + wave * 64) * 16], Agn + st_off[it]);
                async_copy16(&Bs[nxt][(it * 256 + wave * 64) * 16], Bgn + st_off[it]);
            }
            if (t < 32)
                async_copy16(&xs_lds[nxt][0], xs_t + (size_t)(kb + 1) * M + m0 + t * 4);
        }

        const float wskb = ws[wsrow + kb];   // uniform -> s_load

        // fragments from current buffer (lgkm waits via data dep; no barrier)
        v4i a0[4], a1[4], b0[4], b1[4];
        float4 xs4[4];
#pragma unroll
        for (int i = 0; i < 4; ++i) {
            const int r = (wm + i * 16 + frow) * 128;
            a0[i] = *(const v4i*)&As[cur][r + sw0];
            a1[i] = *(const v4i*)&As[cur][r + (sw0 ^ 64)];
        }
#pragma unroll
        for (int j = 0; j < 4; ++j) {
            const int r = (wn + j * 16 + frow) * 128;
            b0[j] = *(const v4i*)&Bs[cur][r + sw0];
            b1[j] = *(const v4i*)&Bs[cur][r + (sw0 ^ 64)];
        }
#pragma unroll
        for (int i = 0; i < 4; ++i)
            xs4[i] = *(const float4*)&xs_lds[cur][wm + i * 16 + quad4];

        // MFMA + dequant, loosely scheduled (compiler interleaves pipes)
#pragma unroll
        for (int i = 0; i < 4; ++i) {
            const float s0 = xs4[i].x * wskb, s1 = xs4[i].y * wskb;
            const float s2 = xs4[i].z * wskb, s3 = xs4[i].w * wskb;
#pragma unroll
            for (int j = 0; j < 4; ++j) {
                v4i d = __builtin_amdgcn_mfma_i32_16x16x64_i8(a0[i], b0[j], (v4i){0, 0, 0, 0}, 0, 0, 0);
                d = __builtin_amdgcn_mfma_i32_16x16x64_i8(a1[i], b1[j], d, 0, 0, 0);
                facc[i][j].x += (float)d[0] * s0;
                facc[i][j].y += (float)d[1] * s1;
                facc[i][j].z += (float)d[2] * s2;
                facc[i][j].w += (float)d[3] * s3;
            }
        }

        // single boundary: drains next-kb stages (issued ~1 iter ago) and
        // ensures all waves finished reading buffer `cur` before overwrite
        __syncthreads();
    }

    // epilogue: C/D layout col = lane&15, row = (lane>>4)*4 + reg
    float bj[4];
#pragma unroll
    for (int j = 0; j < 4; ++j) bj[j] = bias[n0 + wn + j * 16 + frow];
#pragma unroll
    for (int i = 0; i < 4; ++i) {
#pragma unroll
        for (int r = 0; r < 4; ++r) {
            const int row = m0 + wm + i * 16 + quad4 + r;
            float* orow = out + (size_t)row * N_DIM + n0 + wn + frow;
#pragma unroll
            for (int j = 0; j < 4; ++j)
                orow[j * 16] = ((const float*)&facc[i][j])[r] + bj[j];
        }
    }
}

extern "C" void kernel_launch(void* const* d_in, const int* in_sizes, int n_in,
                              void* d_out, int out_size, void* d_ws, size_t ws_size,
                              hipStream_t stream)
{
    const float* x    = (const float*)d_in[0];
    const float* w    = (const float*)d_in[1];
    const float* bias = (const float*)d_in[2];
    float* out = (float*)d_out;
    const int M = in_sizes[0] / K_DIM;   // 8192

    int8_t* xq  = (int8_t*)d_ws;                                 // M*K
    int8_t* wqp = xq + (size_t)M * K_DIM;                        // N*K
    float*  xst = (float*)(wqp + (size_t)N_DIM * K_DIM);         // KB*M  [kb][M]
    float*  wsp = xst + (size_t)KB * M;                          // (N/128)*KB

    act_quant_kernel<<<2048, 256, 0, stream>>>(x, xq, xst, M);
    weight_quant_kernel<<<(N_DIM / 128) * KB, 256, 0, stream>>>(w, wqp, wsp);
    gemm_kernel<<<(N_DIM / 128) * (M / 128), 256, 0, stream>>>(
        xq, wqp, xst, wsp, bias, out, M);
}